// Round 6
// baseline (1420135.254 us; speedup 1.0000x reference)
//
#include <hip/hip_runtime.h>

// ---------------------------------------------------------------------------
// ReLU-RNN (B=256, T=512, I=64, H=512, O=24), fp32 in/out.  Round 6.
//
// 16 groups (16 batch rows) x 8 members (64 hid cols) = 128 blocks x 256 thr.
// FLAG-FREE exchange: h is exchanged as fp32 with the SIGN BIT as a freshness
// tag (h>=0 after relu). Tag = ((t+1)>>1)&1 alternates on each rewrite of a
// slab (double-buffered), so stale data (incl. 0xAA poison) never matches.
// Consumers poll the data itself (dwordx4 sc0 sc1); producers issue 4
// coalesced tagged dword stores per lane with NO drain wait and no flag.
// Seeing tagged h_{t+1} proves the producer consumed h_t => skew<=1, no
// overwrite hazard. 2 barriers/step. W_ext=[W_hh|W_ih] (K=576) in VGPRs as
// bf16 hi/lo MFMA B-frags; bf16x3 MFMA from LDS-staged A=[h|x_t].
// ---------------------------------------------------------------------------

#define T_STEPS 512
#define NG      16
#define NM      8
#define SLAB    32768                    // 16 rows x 512 cols fp32
#define POLL_CAP 20000

#define LA_STRIDE 1040                   // bytes; 65 x 16B (odd) for b128 reads
#define LA_PLANE  16640                  // 16*1040
#define LX_OFF    33280                  // 2*LA_PLANE
#define LX_STRIDE 144
#define LX_PLANE  2304                   // 16*144  (total LDS 37888 B)

typedef short          short8  __attribute__((ext_vector_type(8)));
typedef unsigned       uintx4  __attribute__((ext_vector_type(4)));
typedef float          floatx4 __attribute__((ext_vector_type(4)));
typedef unsigned long long ull;

__device__ __forceinline__ unsigned short f2bf(float x) {
    unsigned u = __float_as_uint(x);
    u = (u + 0x7fffu + ((u >> 16) & 1u)) >> 16;   // RNE
    return (unsigned short)u;
}
__device__ __forceinline__ float bf2f(unsigned short h) {
    return __uint_as_float(((unsigned)h) << 16);
}
// L3-coherence-point (bypass L1+L2) ops
__device__ __forceinline__ uintx4 ld_l3_b128_async(const void* p) {
    uintx4 v;
    asm volatile("global_load_dwordx4 %0, %1, off sc0 sc1"
                 : "=v"(v) : "v"(p) : "memory");
    return v;
}
__device__ __forceinline__ void st_l3_b32(void* p, unsigned v) {
    asm volatile("global_store_dword %0, %1, off sc0 sc1"
                 :: "v"(p), "v"(v) : "memory");
}
__device__ __forceinline__ void st_l3_b128(void* p, uintx4 v) {
    asm volatile("global_store_dwordx4 %0, %1, off sc0 sc1"
                 :: "v"(p), "v"(v) : "memory");
}
__device__ __forceinline__ void wait_vm0() {
    asm volatile("s_waitcnt vmcnt(0)" ::: "memory");
}

__global__ __launch_bounds__(256, 1) void rnn_persistent(
    const float* __restrict__ x,     const float* __restrict__ W_ih,
    const float* __restrict__ W_hh,  const float* __restrict__ b_ih,
    const float* __restrict__ b_hh,  const float* __restrict__ fc_w,
    const float* __restrict__ fc_b,  float* __restrict__ out,
    unsigned char* __restrict__ ws)
{
    const int tid  = threadIdx.x;
    const int lane = tid & 63;
    const int w    = tid >> 6;        // wave 0..3
    const int n    = lane & 15;
    const int quad = lane >> 4;

    const int bid = blockIdx.x;
    const int g = bid >> 3;           // group 0..15
    const int m = bid & 7;            // member 0..7

    unsigned char* ex = (unsigned char*)ws;
    __shared__ __align__(16) unsigned char smem[LX_OFF + 2 * LX_PLANE];

    // ---- W fragments: wave w holds cols (=W rows) m*64+w*16 .. +16 ----
    const int wrow = m * 64 + w * 16 + n;
    short8 Whi[18], Wlo[18];
    #pragma unroll
    for (int kt = 0; kt < 18; ++kt) {
        const float* p = (kt < 16) ? (W_hh + wrow * 512 + kt * 32 + quad * 8)
                                   : (W_ih + wrow * 64 + (kt - 16) * 32 + quad * 8);
        #pragma unroll
        for (int jj = 0; jj < 8; ++jj) {
            float f = p[jj];
            unsigned short h = f2bf(f);
            Whi[kt][jj] = (short)h;
            Wlo[kt][jj] = (short)f2bf(f - bf2f(h));
        }
    }
    const float bias_i = b_ih[wrow] + b_hh[wrow];

    // ---- poll span mapping: thread -> (row, 16B col-span) of each partner --
    const int prow = tid >> 4, pc4 = tid & 15;
    int poff[7];
    #pragma unroll
    for (int r = 0; r < 7; ++r) {
        const int pm = r + (r >= m ? 1 : 0);
        poff[r] = prow * 2048 + pm * 256 + pc4 * 16;
    }

    // ---- init: own chunk = tagged(+0.0, tag0) in slab parity0; own cols = 0
    //      in LDS A planes. No barrier/flag needed (consumers poll data). ----
    {
        uintx4 z = {0u, 0u, 0u, 0u};
        st_l3_b128(ex + g * SLAB + prow * 2048 + m * 256 + pc4 * 16, z);
        #pragma unroll
        for (int r = 0; r < 4; ++r) {
            const int row = quad * 4 + r;
            *(unsigned short*)(smem + 0 * LA_PLANE + row * LA_STRIDE + wrow * 2) = 0;
            *(unsigned short*)(smem + 1 * LA_PLANE + row * LA_STRIDE + wrow * 2) = 0;
        }
    }

    // ---- recurrence ------------------------------------------------------
    const int xrow = tid >> 4, xi4 = tid & 15;
    for (int t = 0; t < T_STEPS; ++t) {
        // x_t prefetch (no dependence on partners)
        const float4 xv = *(const float4*)
            (x + ((size_t)(g * 16 + xrow) * T_STEPS + t) * 64 + xi4 * 4);

        // poll partner data until all 28 sign bits match expected tag
        const unsigned texp = (((unsigned)t >> 1) & 1u) << 31;
        const unsigned char* slab_r = ex + ((t & 1) * NG + g) * SLAB;
        uintx4 P[7];
        {
            int it = 0;
            for (;;) {
                #pragma unroll
                for (int r = 0; r < 7; ++r)
                    P[r] = ld_l3_b128_async(slab_r + poff[r]);
                wait_vm0();
                unsigned bad = 0;
                #pragma unroll
                for (int r = 0; r < 7; ++r)
                    bad |= (P[r].x ^ texp) | (P[r].y ^ texp)
                         | (P[r].z ^ texp) | (P[r].w ^ texp);
                if (!(bad & 0x80000000u) || ++it >= POLL_CAP) break;
            }
        }

        // stage partner cols -> LDS A planes (strip tag, split bf16 hi/lo)
        #pragma unroll
        for (int r = 0; r < 7; ++r) {
            const int pm = r + (r >= m ? 1 : 0);
            ull hi = 0, lo = 0;
            #pragma unroll
            for (int j = 0; j < 4; ++j) {
                const float f = __uint_as_float(P[r][j] & 0x7fffffffu);
                const unsigned short hs = f2bf(f);
                const unsigned short ls = f2bf(f - bf2f(hs));
                hi |= (ull)hs << (16 * j);
                lo |= (ull)ls << (16 * j);
            }
            const int base = prow * LA_STRIDE + pm * 128 + pc4 * 8;
            *(ull*)(smem + base)            = hi;
            *(ull*)(smem + LA_PLANE + base) = lo;
        }
        // stage x_t (fp32 -> bf16 hi/lo)
        {
            ull hi = 0, lo = 0;
            #pragma unroll
            for (int k = 0; k < 4; ++k) {
                const float f = (k == 0) ? xv.x : (k == 1) ? xv.y : (k == 2) ? xv.z : xv.w;
                const unsigned short hs = f2bf(f);
                const unsigned short ls = f2bf(f - bf2f(hs));
                hi |= (ull)hs << (16 * k);
                lo |= (ull)ls << (16 * k);
            }
            *(ull*)(smem + LX_OFF + xrow * LX_STRIDE + xi4 * 8)            = hi;
            *(ull*)(smem + LX_OFF + LX_PLANE + xrow * LX_STRIDE + xi4 * 8) = lo;
        }
        __syncthreads();                                   // (c) stage done

        // MFMA: C[16 batch x 16 cols] over K=576, bf16x3
        floatx4 c0 = {0.f,0.f,0.f,0.f}, c1 = {0.f,0.f,0.f,0.f}, c2 = {0.f,0.f,0.f,0.f};
        #pragma unroll
        for (int kt = 0; kt < 16; ++kt) {
            const unsigned char* ba = smem + n * LA_STRIDE + kt * 64 + quad * 16;
            short8 ah = *(const short8*)(ba);
            short8 al = *(const short8*)(ba + LA_PLANE);
            c0 = __builtin_amdgcn_mfma_f32_16x16x32_bf16(ah, Whi[kt], c0, 0, 0, 0);
            c1 = __builtin_amdgcn_mfma_f32_16x16x32_bf16(al, Whi[kt], c1, 0, 0, 0);
            c2 = __builtin_amdgcn_mfma_f32_16x16x32_bf16(ah, Wlo[kt], c2, 0, 0, 0);
        }
        #pragma unroll
        for (int kt = 16; kt < 18; ++kt) {
            const unsigned char* ba = smem + LX_OFF + n * LX_STRIDE + (kt - 16) * 64 + quad * 16;
            short8 ah = *(const short8*)(ba);
            short8 al = *(const short8*)(ba + LX_PLANE);
            c0 = __builtin_amdgcn_mfma_f32_16x16x32_bf16(ah, Whi[kt], c0, 0, 0, 0);
            c1 = __builtin_amdgcn_mfma_f32_16x16x32_bf16(al, Whi[kt], c1, 0, 0, 0);
            c2 = __builtin_amdgcn_mfma_f32_16x16x32_bf16(ah, Wlo[kt], c2, 0, 0, 0);
        }
        __syncthreads();                                   // (e1) reads done

        // epilogue: own cols -> LDS (next step) + tagged fp32 -> global.
        // No drain wait, no flag: data is self-signalling.
        const unsigned otag = ((((unsigned)t + 1u) >> 1) & 1u) << 31;
        unsigned char* slab_w = ex + (((t + 1) & 1) * NG + g) * SLAB;
        const floatx4 cs = c0 + c1 + c2;
        #pragma unroll
        for (int r = 0; r < 4; ++r) {
            float v = cs[r] + bias_i;
            v = v > 0.f ? v : 0.f;
            const int row = quad * 4 + r;
            const unsigned short h = f2bf(v);
            const unsigned short l = f2bf(v - bf2f(h));
            *(unsigned short*)(smem + 0 * LA_PLANE + row * LA_STRIDE + wrow * 2) = h;
            *(unsigned short*)(smem + 1 * LA_PLANE + row * LA_STRIDE + wrow * 2) = l;
            st_l3_b32(slab_w + row * 2048 + wrow * 4, __float_as_uint(v) | otag);
        }
    }

    // ---- fc on h_512 (member 0 only; own cols already in LDS) ------------
    if (m != 0) return;
    {
        const unsigned texp = (((unsigned)T_STEPS >> 1) & 1u) << 31;   // 0
        const unsigned char* slab_r = ex + ((T_STEPS & 1) * NG + g) * SLAB;
        uintx4 P[7];
        int it = 0;
        for (;;) {
            #pragma unroll
            for (int r = 0; r < 7; ++r)
                P[r] = ld_l3_b128_async(slab_r + poff[r]);
            wait_vm0();
            unsigned bad = 0;
            #pragma unroll
            for (int r = 0; r < 7; ++r)
                bad |= (P[r].x ^ texp) | (P[r].y ^ texp)
                     | (P[r].z ^ texp) | (P[r].w ^ texp);
            if (!(bad & 0x80000000u) || ++it >= POLL_CAP) break;
        }
        #pragma unroll
        for (int r = 0; r < 7; ++r) {
            const int pm = r + 1;
            ull hi = 0, lo = 0;
            #pragma unroll
            for (int j = 0; j < 4; ++j) {
                const float f = __uint_as_float(P[r][j] & 0x7fffffffu);
                const unsigned short hs = f2bf(f);
                const unsigned short ls = f2bf(f - bf2f(hs));
                hi |= (ull)hs << (16 * j);
                lo |= (ull)ls << (16 * j);
            }
            const int base = prow * LA_STRIDE + pm * 128 + pc4 * 8;
            *(ull*)(smem + base)            = hi;
            *(ull*)(smem + LA_PLANE + base) = lo;
        }
    }
    __syncthreads();
    typedef unsigned short bfx4 __attribute__((ext_vector_type(4)));
    for (int idx = tid; idx < 384; idx += 256) {
        const int row = idx / 24, o = idx % 24;
        const float* wp = fc_w + o * 512;
        float s = 0.f;
        for (int k = 0; k < 512; k += 4) {
            bfx4 hv = *(const bfx4*)(smem + row * LA_STRIDE + k * 2);
            bfx4 lv = *(const bfx4*)(smem + LA_PLANE + row * LA_STRIDE + k * 2);
            const float4 wv = *(const float4*)(wp + k);
            s += (bf2f(hv[0]) + bf2f(lv[0])) * wv.x;
            s += (bf2f(hv[1]) + bf2f(lv[1])) * wv.y;
            s += (bf2f(hv[2]) + bf2f(lv[2])) * wv.z;
            s += (bf2f(hv[3]) + bf2f(lv[3])) * wv.w;
        }
        out[(g * 16 + row) * 24 + o] = s + fc_b[o];
    }
}

extern "C" void kernel_launch(void* const* d_in, const int* in_sizes, int n_in,
                              void* d_out, int out_size, void* d_ws, size_t ws_size,
                              hipStream_t stream) {
    (void)in_sizes; (void)n_in; (void)out_size; (void)ws_size;
    const float* x    = (const float*)d_in[0];
    const float* W_ih = (const float*)d_in[1];
    const float* W_hh = (const float*)d_in[2];
    const float* b_ih = (const float*)d_in[3];
    const float* b_hh = (const float*)d_in[4];
    const float* fc_w = (const float*)d_in[5];
    const float* fc_b = (const float*)d_in[6];
    rnn_persistent<<<128, 256, 0, stream>>>(x, W_ih, W_hh, b_ih, b_hh,
                                            fc_w, fc_b, (float*)d_out,
                                            (unsigned char*)d_ws);
}

// Round 7
// 1642.035 us; speedup vs baseline: 864.8630x; 864.8630x over previous
//
#include <hip/hip_runtime.h>

// ---------------------------------------------------------------------------
// ReLU-RNN (B=256, T=512, I=64, H=512, O=24), fp32 in/out.  Round 7.
//
// 16 groups (16 batch rows) x 8 members (64 hid cols) = 128 blocks x 256 thr.
// Exchange = tagged fp32 (sign bit = slab-parity tag; h>=0 after relu):
//   * flags (agent-scope, 7 polling threads) throttle the wait   [round-5]
//   * sign-bit tags carry data-freshness correctness             [round-6]
//   * phase-1 SPECULATIVE partner loads issued before the poll --
//     overlaps the data RTT with the park; laggard always hits.
//   * phase-2 bounded per-thread tag-retry fixes stale spans (tiny traffic).
//   * producer: tagged dword stores + flag store with NO vmcnt drain.
// LDS A-planes double-buffered by parity -> 2 barriers/step.
// W_ext=[W_hh|W_ih] (K=576) in VGPRs as bf16 hi/lo frags; bf16x3 MFMA.
// ---------------------------------------------------------------------------

#define T_STEPS 512
#define NG      16
#define NM      8
#define SLAB    32768                    // 16 rows x 512 cols fp32
#define FLAGS_OFF (2 * NG * SLAB)        // 1 MiB
#define NEG_OFF  (FLAGS_OFF + NG * 64)
#define POLL_CAP 100000
#define TAG_CAP  20000
#define NEG_CAP  20000000

// LDS: A planes double-buffered by parity; rows 16 x 1040B (512 bf16 + 8 pad)
#define LA_STRIDE 1040
#define LA_PLANE  16640                  // 16*1040
#define LA_PAR    33280                  // 2*LA_PLANE (hi+lo)
#define LX_OFF    66560                  // 2*LA_PAR
#define LX_STRIDE 144
#define LX_PLANE  2304                   // 16*144; total 71168 B

typedef short          short8  __attribute__((ext_vector_type(8)));
typedef unsigned short bfx4    __attribute__((ext_vector_type(4)));
typedef unsigned       uintx4  __attribute__((ext_vector_type(4)));
typedef float          floatx4 __attribute__((ext_vector_type(4)));
typedef unsigned long long ull;

__device__ __forceinline__ unsigned short f2bf(float x) {
    unsigned u = __float_as_uint(x);
    u = (u + 0x7fffu + ((u >> 16) & 1u)) >> 16;   // RNE
    return (unsigned short)u;
}
__device__ __forceinline__ float bf2f(unsigned short h) {
    return __uint_as_float(((unsigned)h) << 16);
}
__device__ __forceinline__ void st_ag_u32(void* p, unsigned v) {
    __hip_atomic_store((unsigned*)p, v, __ATOMIC_RELAXED, __HIP_MEMORY_SCOPE_AGENT);
}
__device__ __forceinline__ unsigned ld_ag_u32(const void* p) {
    return __hip_atomic_load((const unsigned*)p, __ATOMIC_RELAXED, __HIP_MEMORY_SCOPE_AGENT);
}
// L3-coherence-point (bypass L1+L2) data ops
__device__ __forceinline__ uintx4 ld_l3_b128_async(const void* p) {
    uintx4 v;
    asm volatile("global_load_dwordx4 %0, %1, off sc0 sc1"
                 : "=v"(v) : "v"(p) : "memory");
    return v;
}
__device__ __forceinline__ void st_l3_b32(void* p, unsigned v) {
    asm volatile("global_store_dword %0, %1, off sc0 sc1"
                 :: "v"(p), "v"(v) : "memory");
}
__device__ __forceinline__ void st_l3_b128(void* p, uintx4 v) {
    asm volatile("global_store_dwordx4 %0, %1, off sc0 sc1"
                 :: "v"(p), "v"(v) : "memory");
}
__device__ __forceinline__ void wait_vm0() {
    asm volatile("s_waitcnt vmcnt(0)" ::: "memory");
}
__device__ __forceinline__ void poll_flag(const unsigned* p, unsigned want) {
    int it = 0;
    for (;;) {
        unsigned f = ld_ag_u32(p);
        if (f == want || f == want + 1u) return;
        if (++it >= POLL_CAP) return;            // tags still protect data
    }
}

__global__ __launch_bounds__(256, 1) void rnn_persistent(
    const float* __restrict__ x,     const float* __restrict__ W_ih,
    const float* __restrict__ W_hh,  const float* __restrict__ b_ih,
    const float* __restrict__ b_hh,  const float* __restrict__ fc_w,
    const float* __restrict__ fc_b,  float* __restrict__ out,
    unsigned char* __restrict__ ws)
{
    const int tid  = threadIdx.x;
    const int lane = tid & 63;
    const int w    = tid >> 6;        // wave 0..3
    const int n    = lane & 15;
    const int quad = lane >> 4;

    const int bid = blockIdx.x;
    const int g = bid >> 3;           // group 0..15
    const int m = bid & 7;            // member 0..7

    unsigned char* ex = (unsigned char*)ws;
    unsigned* flagbase = (unsigned*)(ex + FLAGS_OFF + g * 64);
    __shared__ __align__(16) unsigned char smem[LX_OFF + 2 * LX_PLANE];
    __shared__ unsigned sh_nonce;

    // ---- nonce publish (single self-validating dword: low byte 0x5B) ----
    unsigned* nonce_p = (unsigned*)(ex + NEG_OFF);
    if (tid == 0) {
        if (bid == 0) {
            unsigned nn = ((unsigned)__builtin_amdgcn_s_memrealtime() << 8) | 0x5Bu;
            st_ag_u32(nonce_p, nn);
        }
        unsigned v; int it = 0;
        do { v = ld_ag_u32(nonce_p); } while ((v & 0xFFu) != 0x5Bu && ++it < NEG_CAP);
        sh_nonce = v;
    }
    __syncthreads();
    const unsigned nonce = sh_nonce;

    // ---- W fragments: wave w holds cols (=W rows) m*64+w*16 .. +16 ----
    const int wrow = m * 64 + w * 16 + n;
    short8 Whi[18], Wlo[18];
    #pragma unroll
    for (int kt = 0; kt < 18; ++kt) {
        const float* p = (kt < 16) ? (W_hh + wrow * 512 + kt * 32 + quad * 8)
                                   : (W_ih + wrow * 64 + (kt - 16) * 32 + quad * 8);
        #pragma unroll
        for (int jj = 0; jj < 8; ++jj) {
            float f = p[jj];
            unsigned short h = f2bf(f);
            Whi[kt][jj] = (short)h;
            Wlo[kt][jj] = (short)f2bf(f - bf2f(h));
        }
    }
    const float bias_i = b_ih[wrow] + b_hh[wrow];

    // ---- per-thread partner span mapping (row prow, 16B at pc4) ----
    const int prow = tid >> 4, pc4 = tid & 15;
    int poff[7];
    #pragma unroll
    for (int r = 0; r < 7; ++r) {
        const int pm = r + (r >= m ? 1 : 0);
        poff[r] = prow * 2048 + pm * 256 + pc4 * 16;
    }

    // ---- init: own chunk = +0.0 (tag0) in parity-0 slab; own LDS cols = 0
    {
        uintx4 z = {0u, 0u, 0u, 0u};
        st_l3_b128(ex + g * SLAB + prow * 2048 + m * 256 + pc4 * 16, z);
        #pragma unroll
        for (int r = 0; r < 4; ++r) {
            const int row = quad * 4 + r;
            *(unsigned short*)(smem + 0 * LA_PLANE + row * LA_STRIDE + wrow * 2) = 0;
            *(unsigned short*)(smem + LA_PLANE + row * LA_STRIDE + wrow * 2) = 0;
        }
    }
    wait_vm0();
    __syncthreads();
    if (tid == 0) st_ag_u32(flagbase + m, nonce);

    // ---- recurrence ------------------------------------------------------
    const int xrow = tid >> 4, xi4 = tid & 15;
    for (int t = 0; t < T_STEPS; ++t) {
        const unsigned texp = (((unsigned)t >> 1) & 1u) << 31;
        const unsigned char* slab_r = ex + ((t & 1) * NG + g) * SLAB;

        // phase-1: speculative partner loads (overlap the flag park)
        uintx4 P[7];
        #pragma unroll
        for (int r = 0; r < 7; ++r) P[r] = ld_l3_b128_async(slab_r + poff[r]);
        // x_t load (independent, cacheable)
        const float4 xv = *(const float4*)
            (x + ((size_t)(g * 16 + xrow) * T_STEPS + t) * 64 + xi4 * 4);

        // flag park (7 threads only - no data-poll storm)
        if (tid < 7) {
            const int pm = tid + (tid >= m ? 1 : 0);
            poll_flag(flagbase + pm, nonce + (unsigned)t);
        }
        wait_vm0();
        __syncthreads();                                   // (a)

        // phase-2: bounded per-thread tag-retry for stale spans
        {
            int it = 0;
            for (;;) {
                unsigned bad = 0;
                #pragma unroll
                for (int r = 0; r < 7; ++r)
                    bad |= (P[r].x ^ texp) | (P[r].y ^ texp)
                         | (P[r].z ^ texp) | (P[r].w ^ texp);
                if (!(bad & 0x80000000u) || ++it >= TAG_CAP) break;
                #pragma unroll
                for (int r = 0; r < 7; ++r) P[r] = ld_l3_b128_async(slab_r + poff[r]);
                wait_vm0();
            }
        }

        // convert partner cols -> LDS A planes (parity t&1)
        unsigned char* abase = smem + (t & 1) * LA_PAR;
        #pragma unroll
        for (int r = 0; r < 7; ++r) {
            const int pm = r + (r >= m ? 1 : 0);
            ull hi = 0, lo = 0;
            #pragma unroll
            for (int j = 0; j < 4; ++j) {
                const float f = __uint_as_float(P[r][j] & 0x7fffffffu);
                const unsigned short hs = f2bf(f);
                const unsigned short ls = f2bf(f - bf2f(hs));
                hi |= (ull)hs << (16 * j);
                lo |= (ull)ls << (16 * j);
            }
            const int base = prow * LA_STRIDE + pm * 128 + pc4 * 8;
            *(ull*)(abase + base)            = hi;
            *(ull*)(abase + LA_PLANE + base) = lo;
        }
        // stage x_t (fp32 -> bf16 hi/lo)
        {
            ull hi = 0, lo = 0;
            #pragma unroll
            for (int k = 0; k < 4; ++k) {
                const float f = (k == 0) ? xv.x : (k == 1) ? xv.y : (k == 2) ? xv.z : xv.w;
                const unsigned short hs = f2bf(f);
                const unsigned short ls = f2bf(f - bf2f(hs));
                hi |= (ull)hs << (16 * k);
                lo |= (ull)ls << (16 * k);
            }
            *(ull*)(smem + LX_OFF + xrow * LX_STRIDE + xi4 * 8)            = hi;
            *(ull*)(smem + LX_OFF + LX_PLANE + xrow * LX_STRIDE + xi4 * 8) = lo;
        }
        __syncthreads();                                   // (b)

        // MFMA: C[16 batch x 16 cols] over K=576, bf16x3
        floatx4 c0 = {0.f,0.f,0.f,0.f}, c1 = {0.f,0.f,0.f,0.f}, c2 = {0.f,0.f,0.f,0.f};
        #pragma unroll
        for (int kt = 0; kt < 16; ++kt) {
            const unsigned char* ba = abase + n * LA_STRIDE + kt * 64 + quad * 16;
            short8 ah = *(const short8*)(ba);
            short8 al = *(const short8*)(ba + LA_PLANE);
            c0 = __builtin_amdgcn_mfma_f32_16x16x32_bf16(ah, Whi[kt], c0, 0, 0, 0);
            c1 = __builtin_amdgcn_mfma_f32_16x16x32_bf16(al, Whi[kt], c1, 0, 0, 0);
            c2 = __builtin_amdgcn_mfma_f32_16x16x32_bf16(ah, Wlo[kt], c2, 0, 0, 0);
        }
        #pragma unroll
        for (int kt = 16; kt < 18; ++kt) {
            const unsigned char* ba = smem + LX_OFF + n * LX_STRIDE + (kt - 16) * 64 + quad * 16;
            short8 ah = *(const short8*)(ba);
            short8 al = *(const short8*)(ba + LX_PLANE);
            c0 = __builtin_amdgcn_mfma_f32_16x16x32_bf16(ah, Whi[kt], c0, 0, 0, 0);
            c1 = __builtin_amdgcn_mfma_f32_16x16x32_bf16(al, Whi[kt], c1, 0, 0, 0);
            c2 = __builtin_amdgcn_mfma_f32_16x16x32_bf16(ah, Wlo[kt], c2, 0, 0, 0);
        }

        // epilogue: own cols h_{t+1} -> LDS parity (t+1)&1 + tagged global.
        // NO drain, NO wait: tags carry freshness; flag is only a throttle.
        const unsigned otag = ((((unsigned)t + 1u) >> 1) & 1u) << 31;
        unsigned char* slab_w = ex + (((t + 1) & 1) * NG + g) * SLAB;
        unsigned char* obase  = smem + ((t + 1) & 1) * LA_PAR;
        const floatx4 cs = c0 + c1 + c2;
        #pragma unroll
        for (int r = 0; r < 4; ++r) {
            float v = cs[r] + bias_i;
            v = v > 0.f ? v : 0.f;
            const int row = quad * 4 + r;
            const unsigned short h = f2bf(v);
            const unsigned short l = f2bf(v - bf2f(h));
            *(unsigned short*)(obase + row * LA_STRIDE + wrow * 2) = h;
            *(unsigned short*)(obase + LA_PLANE + row * LA_STRIDE + wrow * 2) = l;
            st_l3_b32(slab_w + row * 2048 + wrow * 4, __float_as_uint(v) | otag);
        }
        if (tid == 0) st_ag_u32(flagbase + m, nonce + (unsigned)t + 1u);
    }

    // ---- fc on h_512 (member 0 only; own cols already in LDS parity 0) ---
    if (m != 0) return;
    {
        const unsigned texp = 0;                           // tag of h_512
        const unsigned char* slab_r = ex + (0 * NG + g) * SLAB;
        uintx4 P[7];
        #pragma unroll
        for (int r = 0; r < 7; ++r) P[r] = ld_l3_b128_async(slab_r + poff[r]);
        if (tid < 7) poll_flag(flagbase + (tid + 1), nonce + (unsigned)T_STEPS);
        wait_vm0();
        __syncthreads();
        int it = 0;
        for (;;) {
            unsigned bad = 0;
            #pragma unroll
            for (int r = 0; r < 7; ++r)
                bad |= (P[r].x ^ texp) | (P[r].y ^ texp)
                     | (P[r].z ^ texp) | (P[r].w ^ texp);
            if (!(bad & 0x80000000u) || ++it >= TAG_CAP) break;
            #pragma unroll
            for (int r = 0; r < 7; ++r) P[r] = ld_l3_b128_async(slab_r + poff[r]);
            wait_vm0();
        }
        unsigned char* abase = smem;                       // parity 0
        #pragma unroll
        for (int r = 0; r < 7; ++r) {
            const int pm = r + 1;
            ull hi = 0, lo = 0;
            #pragma unroll
            for (int j = 0; j < 4; ++j) {
                const float f = __uint_as_float(P[r][j] & 0x7fffffffu);
                const unsigned short hs = f2bf(f);
                const unsigned short ls = f2bf(f - bf2f(hs));
                hi |= (ull)hs << (16 * j);
                lo |= (ull)ls << (16 * j);
            }
            const int base = prow * LA_STRIDE + pm * 128 + pc4 * 8;
            *(ull*)(abase + base)            = hi;
            *(ull*)(abase + LA_PLANE + base) = lo;
        }
    }
    __syncthreads();
    for (int idx = tid; idx < 384; idx += 256) {
        const int row = idx / 24, o = idx % 24;
        const float* wp = fc_w + o * 512;
        float s = 0.f;
        for (int k = 0; k < 512; k += 4) {
            bfx4 hv = *(const bfx4*)(smem + row * LA_STRIDE + k * 2);
            bfx4 lv = *(const bfx4*)(smem + LA_PLANE + row * LA_STRIDE + k * 2);
            const float4 wv = *(const float4*)(wp + k);
            s += (bf2f(hv[0]) + bf2f(lv[0])) * wv.x;
            s += (bf2f(hv[1]) + bf2f(lv[1])) * wv.y;
            s += (bf2f(hv[2]) + bf2f(lv[2])) * wv.z;
            s += (bf2f(hv[3]) + bf2f(lv[3])) * wv.w;
        }
        out[(g * 16 + row) * 24 + o] = s + fc_b[o];
    }
}

extern "C" void kernel_launch(void* const* d_in, const int* in_sizes, int n_in,
                              void* d_out, int out_size, void* d_ws, size_t ws_size,
                              hipStream_t stream) {
    (void)in_sizes; (void)n_in; (void)out_size; (void)ws_size;
    const float* x    = (const float*)d_in[0];
    const float* W_ih = (const float*)d_in[1];
    const float* W_hh = (const float*)d_in[2];
    const float* b_ih = (const float*)d_in[3];
    const float* b_hh = (const float*)d_in[4];
    const float* fc_w = (const float*)d_in[5];
    const float* fc_b = (const float*)d_in[6];
    rnn_persistent<<<128, 256, 0, stream>>>(x, W_ih, W_hh, b_ih, b_hh,
                                            fc_w, fc_b, (float*)d_out,
                                            (unsigned char*)d_ws);
}